// Round 8
// baseline (163.996 us; speedup 1.0000x reference)
//
#include <hip/hip_runtime.h>

// Problem constants (fixed by reference)
#define BB 8
#define NN 128
#define CC 64
#define NT 16                  // i/j tiles of 8 -> 16 tiles, 136 unordered pairs
static constexpr float INV_A = 1.0f / 49.0f;   // average_nobj = 49.0

// Workspace layout (float offsets)
#define OFF_C    0           // C[b][d][s], 15*64*64 fp32 (for S/DG paths)
#define OFF_CB   61440       // Cb bf16 [s][k=128]: k<64 -> C3[d][s], k>=64 -> C4[d][s]
#define OFF_CU1  65536       // CU1b bf16 [s][k=192]: k=f*64+d, f in {dv(C1),rs(C9),cs(C11)}
#define OFF_CU2  71680       // CU2b bf16 [s][k=192]: f in {dv(C2),rs(C10),cs(C12)}
#define OFF_RS   77824       // rowsum/A  [n][i][d]
#define OFF_CS   143360      // colsum/A  [n][j][d]
#define OFF_DV   208896      // diag      [n][i][d]
#define OFF_XB   274432      // x bf16 [n][i][j][d]  (8.4M bf16 = 16.8 MB)

typedef __attribute__((ext_vector_type(8))) short v8s;
typedef __attribute__((ext_vector_type(4))) float v4f;

// pack two fp32 -> one dword of two bf16 (round-half-up; err <= 2^-9 rel)
static __device__ inline unsigned pack2bf(float a, float b) {
    union { float f; unsigned u; } ua, ub; ua.f = a; ub.f = b;
    return ((ua.u + 0x8000u) >> 16) | ((ub.u + 0x8000u) & 0xffff0000u);
}
static __device__ inline unsigned short f2bf(float a) {
    union { float f; unsigned u; } ua; ua.f = a;
    return (unsigned short)((ua.u + 0x8000u) >> 16);
}
static __device__ inline float bf2f(unsigned short h) {
    union { unsigned u; float f; } c; c.u = ((unsigned)h) << 16; return c.f;
}

// ---------------------------------------------------------------------------
// K_pre: blocks [0,256) rowsum+diag+XB-emit; [256,512) colsum;
// [512,880) coefficient tables: 368*256 = 94208 = 61440(C) + 8192(Cb) + 24576(CU).
__global__ void k_pre(const float* __restrict__ in,
                      const float* __restrict__ c00, const float* __restrict__ c01,
                      const float* __restrict__ c10, const float* __restrict__ c11,
                      float* __restrict__ ws) {
    if (blockIdx.x >= 512) {
        int idx = (blockIdx.x - 512) * 256 + threadIdx.x;
        if (idx < 61440) {
            int b = idx >> 12; int r = idx & 4095; int d = r >> 6; int s = r & 63;
            ws[OFF_C + idx] = c00[d * 15 + b] * c10[d * 64 + s] + c01[s * 15 + b] * c11[d * 64 + s];
        } else if (idx < 69632) {
            int k = idx - 61440;
            int which = k >> 12;           // 0 -> b=3 (identity), 1 -> b=4 (transpose)
            int r = k & 4095; int s = r >> 6; int d = r & 63;
            int b = 3 + which;
            float v = c00[d * 15 + b] * c10[d * 64 + s] + c01[s * 15 + b] * c11[d * 64 + s];
            unsigned short* cb = (unsigned short*)(ws + OFF_CB);
            cb[s * 128 + which * 64 + d] = f2bf(v);
        } else {
            int e = idx - 69632;           // 0..24575
            int which = e >= 12288;
            int r = which ? e - 12288 : e;
            int s = r / 192; int k = r - s * 192;
            int f = k >> 6; int d = k & 63;
            const int b1[3] = {1, 9, 11}, b2[3] = {2, 10, 12};
            int b = which ? b2[f] : b1[f];
            float v = c00[d * 15 + b] * c10[d * 64 + s] + c01[s * 15 + b] * c11[d * 64 + s];
            unsigned short* cu = (unsigned short*)(ws + (which ? OFF_CU2 : OFF_CU1));
            cu[s * 192 + k] = f2bf(v);
        }
        return;
    }
    __shared__ float4 part[4][4][16];
    int mode = blockIdx.x >> 8;            // 0 rowsum(+XB emit), 1 colsum
    int bb = blockIdx.x & 255;
    int n = bb >> 5; int g0 = (bb & 31) * 4;
    int t = threadIdx.x;
    int q = t >> 6; int ii = (t >> 4) & 3; int d4 = t & 15;
    float4 acc = make_float4(0.f, 0.f, 0.f, 0.f);
    if (mode == 0) {
        int i = g0 + ii;
        float4 dvv = acc; bool hd = false;
        const float* base = in + ((size_t)(n * NN + i)) * NN * CC + d4 * 4;
        unsigned short* xB = (unsigned short*)(ws + OFF_XB)
                           + ((size_t)(n * NN + i)) * NN * CC + d4 * 4;
        for (int j = q * 32; j < q * 32 + 32; ++j) {
            float4 v = *(const float4*)(base + (size_t)j * CC);
            acc.x += v.x; acc.y += v.y; acc.z += v.z; acc.w += v.w;
            uint2 pk; pk.x = pack2bf(v.x, v.y); pk.y = pack2bf(v.z, v.w);
            *(uint2*)(xB + (size_t)j * CC) = pk;
            if (j == i) { dvv = v; hd = true; }
        }
        if (hd) *(float4*)(ws + OFF_DV + ((size_t)(n * NN + i)) * CC + d4 * 4) = dvv;
    } else {
        int j = g0 + ii;
        for (int i = q * 32; i < q * 32 + 32; ++i) {
            float4 v = *(const float4*)(in + (((size_t)(n * NN + i)) * NN + j) * CC + d4 * 4);
            acc.x += v.x; acc.y += v.y; acc.z += v.z; acc.w += v.w;
        }
    }
    part[q][ii][d4] = acc;
    __syncthreads();
    if (t < 64) {
        int i2 = t >> 4; int dd = t & 15;
        float4 a = part[0][i2][dd], b = part[1][i2][dd], c = part[2][i2][dd], d = part[3][i2][dd];
        float4 s;
        s.x = (a.x + b.x + c.x + d.x) * INV_A;
        s.y = (a.y + b.y + c.y + d.y) * INV_A;
        s.z = (a.z + b.z + c.z + d.z) * INV_A;
        s.w = (a.w + b.w + c.w + d.w) * INV_A;
        *(float4*)(ws + (mode ? OFF_CS : OFF_RS) + ((size_t)(n * NN + g0 + i2)) * CC + dd * 4) = s;
    }
}

// ---------------------------------------------------------------------------
// K_main: fused U-terms + pair-tile GEMM. Block = (n, unordered pair {I,J}).
// Phase 0: stage Bb (main B), Ab (pair A from XB), RVb (16 rows x [dv|rs|cs] bf16),
//          tr/as partials. Phase 1: reduce trL/asL. Phase 2: main MFMA (acc1/acc2),
//          U-MFMA (U1/U2 for the 16 rows, K=192), S (VALU), DG (diag blocks only).
// Phase 3: epilogues via Obuf (aliases Ab).
__global__ __launch_bounds__(256, 3) void k_main(
        const float* __restrict__ mask, const float* __restrict__ bias,
        const float* __restrict__ dbias,
        const float* __restrict__ ws, float* __restrict__ out) {
    __shared__ __align__(16) unsigned char smem[52608];
    unsigned short* Ab  = (unsigned short*)smem;              // 64 x 136 bf16 = 17408
    unsigned short* Bb  = (unsigned short*)(smem + 17408);    // 64 x 136 bf16 = 17408
    unsigned short* RVb = (unsigned short*)(smem + 34816);    // 16 x 200 bf16 = 6400
    float* U1L = (float*)(smem + 41216);                      // 16 x 68 f32 = 4352
    float* U2L = (float*)(smem + 45568);                      // 16 x 68 f32 = 4352
    float* dgL = (float*)(smem + 49920);                      // 8 x 68 f32 = 2176
    float* trL = (float*)(smem + 52096);                      // 64 f32
    float* asL = (float*)(smem + 52352);                      // 64 f32
    float* Obuf = (float*)smem;                               // aliases Ab
    float* trP  = U1L;                                        // scratch 2x4x64 f32, pre-U1L

    int blk = blockIdx.x;
    int n = blk / 136; int rem = blk - n * 136;
    int I = 0;
    { int rr = rem; while (rr >= NT - I) { rr -= NT - I; ++I; } rem = rr; }
    int J = I + rem;
    int i0 = I * 8, j0 = J * 8;
    int t = threadIdx.x;
    int tp = t >> 4; int c = t & 15;

    // ---- phase 0: staging ----
    const unsigned short* cb = (const unsigned short*)(ws + OFF_CB);
    #pragma unroll
    for (int e = 0; e < 4; ++e) {
        int s = e * 16 + tp;
        float4 v = *(const float4*)(cb + s * 128 + c * 8);
        *(float4*)((unsigned char*)(Bb + s * 136 + c * 8)) = v;
    }
    const unsigned short* xb = (const unsigned short*)(ws + OFF_XB);
    #pragma unroll
    for (int e = 0; e < 4; ++e) {
        int idx = e * 256 + t;
        int chunk = idx & 7; int row = idx >> 3;
        int hh = row >> 6; int p = row & 63;
        int ii = p >> 3, jj = p & 7;
        int gi = hh ? (j0 + jj) : (i0 + ii);
        int gj = hh ? (i0 + ii) : (j0 + jj);
        float4 v = *(const float4*)(xb + (((size_t)(n * NN + gi)) * NN + gj) * CC + chunk * 8);
        *(float4*)((unsigned char*)(Ab + p * 136 + hh * 64 + chunk * 8)) = v;
    }
    // RVb: 384 chunks of 8 elems: row(16) x f(3) x ch(8)
    #pragma unroll
    for (int r2 = 0; r2 < 2; ++r2) {
        int ci = t + r2 * 256;
        if (ci < 384) {
            int row = ci / 24; int remc = ci - row * 24;
            int f = remc >> 3; int ch = remc & 7;
            int grow = row < 8 ? (i0 + row) : (j0 + row - 8);
            int foff = (f == 0) ? OFF_DV : (f == 1 ? OFF_RS : OFF_CS);
            const float* src = ws + foff + ((size_t)(n * NN + grow)) * CC + ch * 8;
            float4 a = *(const float4*)(src);
            float4 b = *(const float4*)(src + 4);
            uint4 pk;
            pk.x = pack2bf(a.x, a.y); pk.y = pack2bf(a.z, a.w);
            pk.z = pack2bf(b.x, b.y); pk.w = pack2bf(b.z, b.w);
            *(uint4*)((unsigned char*)(RVb + row * 200 + f * 64 + ch * 8)) = pk;
        }
    }
    // tr/as partials: thread (q = t>>6, s0 = t&63) sums 32 i's
    int q = t >> 6; int s0 = t & 63;
    {
        float pd = 0.f, pr = 0.f;
        #pragma unroll 4
        for (int e = 0; e < 32; ++e) {
            int i = q * 32 + e;
            pd += ws[OFF_DV + ((size_t)(n * NN + i)) * CC + s0];
            pr += ws[OFF_RS + ((size_t)(n * NN + i)) * CC + s0];
        }
        trP[q * 64 + s0] = pd;
        trP[(4 + q) * 64 + s0] = pr;
    }
    __syncthreads();
    // ---- phase 1: reduce trL/asL ----
    if (t < 128) {
        int h = t >> 6; int ss = t & 63;
        const float* p = trP + h * 256;
        float v = p[ss] + p[64 + ss] + p[128 + ss] + p[192 + ss];
        (h ? asL : trL)[ss] = v * INV_A;
    }
    __syncthreads();

    // ---- phase 2: compute ----
    int w = t >> 6; int l = t & 63;
    int r16 = l & 15; int quad = l >> 4;
    int arow = w * 16 + r16;
    v8s af[4];
    #pragma unroll
    for (int kk = 0; kk < 4; ++kk)
        af[kk] = *(const v8s*)(Ab + arow * 136 + kk * 32 + quad * 8);
    v4f acc1[4], acc2[4];
    #pragma unroll
    for (int st = 0; st < 4; ++st) { acc1[st] = 0.f; acc2[st] = 0.f; }
    #pragma unroll
    for (int kk = 0; kk < 4; ++kk) {
        #pragma unroll
        for (int st = 0; st < 4; ++st) {
            v8s bfr = *(const v8s*)(Bb + (st * 16 + r16) * 136 + kk * 32 + quad * 8);
            acc1[st] = __builtin_amdgcn_mfma_f32_16x16x32_bf16(af[kk], bfr, acc1[st], 0, 0, 0);
            acc2[st] = __builtin_amdgcn_mfma_f32_16x16x32_bf16(af[(kk + 2) & 3], bfr, acc2[st], 0, 0, 0);
        }
    }
    // U-MFMA: wave w covers s-tile w. A = CU{1,2}b[s][k], B = RVb[row][k] (transposed-load)
    v4f aU1 = 0.f, aU2 = 0.f;
    {
        const unsigned short* cu1 = (const unsigned short*)(ws + OFF_CU1);
        const unsigned short* cu2 = (const unsigned short*)(ws + OFF_CU2);
        int sg = w * 16 + r16;
        #pragma unroll
        for (int kk = 0; kk < 6; ++kk) {
            v8s a1 = *(const v8s*)(cu1 + sg * 192 + kk * 32 + quad * 8);
            v8s a2 = *(const v8s*)(cu2 + sg * 192 + kk * 32 + quad * 8);
            v8s bv = *(const v8s*)(RVb + r16 * 200 + kk * 32 + quad * 8);
            aU1 = __builtin_amdgcn_mfma_f32_16x16x32_bf16(a1, bv, aU1, 0, 0, 0);
            aU2 = __builtin_amdgcn_mfma_f32_16x16x32_bf16(a2, bv, aU2, 0, 0, 0);
        }
    }
    // S[s] for this thread's 4 s-values (s = c*4 + u)
    float sS[4] = {0.f, 0.f, 0.f, 0.f};
    {
        const float* C13 = ws + OFF_C + 13 * 4096;
        const float* C14 = ws + OFF_C + 14 * 4096;
        for (int d = 0; d < 64; ++d) {
            float4 a = *(const float4*)(C13 + d * 64 + c * 4);
            float4 b = *(const float4*)(C14 + d * 64 + c * 4);
            float tv = trL[d], av = asL[d];
            sS[0] += tv * a.x + av * b.x;
            sS[1] += tv * a.y + av * b.y;
            sS[2] += tv * a.z + av * b.z;
            sS[3] += tv * a.w + av * b.w;
        }
    }
    // DG (only diagonal-pair blocks): rows rg=t>>6 and rg+4, s = s0
    if (I == J) {
        const float* Cb0 = ws + OFF_C;
        float dg0 = 0.f, dg1 = 0.f, dgc = 0.f;
        int rg = t >> 6;
        for (int d = 0; d < 64; ++d) {
            float c0v = Cb0[0 * 4096 + d * 64 + s0];
            float c5v = Cb0[5 * 4096 + d * 64 + s0];
            float c6v = Cb0[6 * 4096 + d * 64 + s0];
            float c7v = Cb0[7 * 4096 + d * 64 + s0];
            float c8v = Cb0[8 * 4096 + d * 64 + s0];
            float dva = bf2f(RVb[rg * 200 + d]);
            float rsa = bf2f(RVb[rg * 200 + 64 + d]);
            float csa = bf2f(RVb[rg * 200 + 128 + d]);
            float dvb = bf2f(RVb[(rg + 4) * 200 + d]);
            float rsb = bf2f(RVb[(rg + 4) * 200 + 64 + d]);
            float csb = bf2f(RVb[(rg + 4) * 200 + 128 + d]);
            dg0 += c0v * dva + c5v * rsa + c6v * csa;
            dg1 += c0v * dvb + c5v * rsb + c6v * csb;
            dgc += c7v * trL[d] + c8v * asL[d];
        }
        float db = dbias[s0];
        dgL[rg * 68 + s0] = dg0 + dgc + db;
        dgL[(rg + 4) * 68 + s0] = dg1 + dgc + db;
    }

    // ---- phase 3: epilogues ----
    // write Obuf (acc1), U1L, U2L; one barrier covers all
    #pragma unroll
    for (int st = 0; st < 4; ++st)
        #pragma unroll
        for (int reg = 0; reg < 4; ++reg)
            Obuf[(w * 16 + quad * 4 + reg) * 68 + st * 16 + r16] = acc1[st][reg];
    #pragma unroll
    for (int reg = 0; reg < 4; ++reg) {
        U1L[r16 * 68 + w * 16 + quad * 4 + reg] = aU1[reg];
        U2L[r16 * 68 + w * 16 + quad * 4 + reg] = aU2[reg];
    }
    __syncthreads();

    float4 bias4 = *(const float4*)(bias + c * 4);
    #pragma unroll
    for (int e = 0; e < 4; ++e) {
        int p = e * 16 + tp;
        int ii = p >> 3, jj = p & 7;
        int gi = i0 + ii, gj = j0 + jj;
        size_t prow = ((size_t)(n * NN + gi));
        float4 v = *(const float4*)(Obuf + p * 68 + c * 4);
        float4 u1 = *(const float4*)(U1L + ii * 68 + c * 4);
        float4 u2 = *(const float4*)(U2L + (8 + jj) * 68 + c * 4);
        v.x += u1.x + u2.x + sS[0] + bias4.x;
        v.y += u1.y + u2.y + sS[1] + bias4.y;
        v.z += u1.z + u2.z + sS[2] + bias4.z;
        v.w += u1.w + u2.w + sS[3] + bias4.w;
        if (gi == gj) {
            float4 dg = *(const float4*)(dgL + ii * 68 + c * 4);
            v.x += dg.x; v.y += dg.y; v.z += dg.z; v.w += dg.w;
        }
        v.x = v.x > 0.f ? v.x : 0.01f * v.x;
        v.y = v.y > 0.f ? v.y : 0.01f * v.y;
        v.z = v.z > 0.f ? v.z : 0.01f * v.z;
        v.w = v.w > 0.f ? v.w : 0.01f * v.w;
        float m = mask[prow * NN + gj];
        v.x *= m; v.y *= m; v.z *= m; v.w *= m;
        *(float4*)(out + (prow * NN + gj) * CC + c * 4) = v;
    }

    if (I == J) return;
    __syncthreads();
    #pragma unroll
    for (int st = 0; st < 4; ++st)
        #pragma unroll
        for (int reg = 0; reg < 4; ++reg)
            Obuf[(w * 16 + quad * 4 + reg) * 68 + st * 16 + r16] = acc2[st][reg];
    __syncthreads();
    #pragma unroll
    for (int e = 0; e < 4; ++e) {
        int p = e * 16 + tp;
        int ii = p >> 3, jj = p & 7;
        int gi = j0 + jj, gj = i0 + ii;      // transposed tile
        size_t prow = ((size_t)(n * NN + gi));
        float4 v = *(const float4*)(Obuf + p * 68 + c * 4);
        float4 u1 = *(const float4*)(U1L + (8 + jj) * 68 + c * 4);
        float4 u2 = *(const float4*)(U2L + ii * 68 + c * 4);
        v.x += u1.x + u2.x + sS[0] + bias4.x;
        v.y += u1.y + u2.y + sS[1] + bias4.y;
        v.z += u1.z + u2.z + sS[2] + bias4.z;
        v.w += u1.w + u2.w + sS[3] + bias4.w;
        // I != J -> gi != gj: no diagonal term
        v.x = v.x > 0.f ? v.x : 0.01f * v.x;
        v.y = v.y > 0.f ? v.y : 0.01f * v.y;
        v.z = v.z > 0.f ? v.z : 0.01f * v.z;
        v.w = v.w > 0.f ? v.w : 0.01f * v.w;
        float m = mask[prow * NN + gj];
        v.x *= m; v.y *= m; v.z *= m; v.w *= m;
        *(float4*)(out + (prow * NN + gj) * CC + c * 4) = v;
    }
}

// ---------------------------------------------------------------------------
extern "C" void kernel_launch(void* const* d_in, const int* in_sizes, int n_in,
                              void* d_out, int out_size, void* d_ws, size_t ws_size,
                              hipStream_t stream) {
    const float* inputs = (const float*)d_in[0];
    const float* mask   = (const float*)d_in[1];
    // d_in[2] = nobj (unused by the reference computation)
    const float* c00 = (const float*)d_in[3];
    const float* c01 = (const float*)d_in[4];
    const float* c10 = (const float*)d_in[5];
    const float* c11 = (const float*)d_in[6];
    const float* bias  = (const float*)d_in[7];
    const float* dbias = (const float*)d_in[8];
    float* out = (float*)d_out;
    float* ws = (float*)d_ws;

    k_pre <<<880, 256, 0, stream>>>(inputs, c00, c01, c10, c11, ws);
    k_main<<<8 * 136, 256, 0, stream>>>(mask, bias, dbias, ws, out);
}

// Round 9
// 134.808 us; speedup vs baseline: 1.2165x; 1.2165x over previous
//
#include <hip/hip_runtime.h>

// Problem constants (fixed by reference)
#define BB 8
#define NN 128
#define CC 64
static constexpr float INV_A = 1.0f / 49.0f;   // average_nobj = 49.0

// Workspace layout (float offsets)
#define OFF_C    0           // C[b][d][s], 15*64*64 fp32 (for k_uv)
#define OFF_CB   61440       // Cb bf16 [s][k=128]: k<64 -> C3[d][s], k>=64 -> C4[d][s]
#define OFF_RS   65536       // rowsum/A  [n][i][d]
#define OFF_CS   131072      // colsum/A  [n][j][d]
#define OFF_DV   196608      // diag      [n][i][d]
#define OFF_U1   263168      // U1 + S + bias      [n][i][s]
#define OFF_U2   328704      // U2                 [n][j][s]
#define OFF_DG   394240      // diag term + dbias  [n][i][s]
#define OFF_XT   459776      // xbT bf16 [n][j][i][d] = x[n,i,j,d]  (8.4M bf16)

typedef __attribute__((ext_vector_type(8))) short v8s;
typedef __attribute__((ext_vector_type(4))) float v4f;

// pack two fp32 -> one dword of two bf16 (round-half-up; err <= 2^-9 rel)
static __device__ inline unsigned pack2bf(float a, float b) {
    union { float f; unsigned u; } ua, ub; ua.f = a; ub.f = b;
    return ((ua.u + 0x8000u) >> 16) | ((ub.u + 0x8000u) & 0xffff0000u);
}
static __device__ inline unsigned short f2bf(float a) {
    union { float f; unsigned u; } ua; ua.f = a;
    return (unsigned short)((ua.u + 0x8000u) >> 16);
}

// ---------------------------------------------------------------------------
// K_pre (R4-validated): blocks [0,256) rowsum+diag; [256,512) colsum + XT emit;
// [512,784) coefficient tables (272*256 = 69632 = 15*4096+8192 exactly).
__global__ void k_pre(const float* __restrict__ in,
                      const float* __restrict__ c00, const float* __restrict__ c01,
                      const float* __restrict__ c10, const float* __restrict__ c11,
                      float* __restrict__ ws) {
    if (blockIdx.x >= 512) {
        int idx = (blockIdx.x - 512) * 256 + threadIdx.x;
        if (idx < 15 * 4096) {
            int b = idx >> 12; int r = idx & 4095; int d = r >> 6; int s = r & 63;
            ws[OFF_C + idx] = c00[d * 15 + b] * c10[d * 64 + s] + c01[s * 15 + b] * c11[d * 64 + s];
        } else if (idx < 15 * 4096 + 8192) {
            int k = idx - 15 * 4096;
            int which = k >> 12;           // 0 -> b=3 (identity), 1 -> b=4 (transpose)
            int r = k & 4095; int s = r >> 6; int d = r & 63;
            int b = 3 + which;
            float v = c00[d * 15 + b] * c10[d * 64 + s] + c01[s * 15 + b] * c11[d * 64 + s];
            unsigned short* cb = (unsigned short*)(ws + OFF_CB);
            cb[s * 128 + which * 64 + d] = f2bf(v);
        }
        return;
    }
    __shared__ float4 part[4][4][16];
    int mode = blockIdx.x >> 8;            // 0 rowsum, 1 colsum(+XT emit)
    int bb = blockIdx.x & 255;
    int n = bb >> 5; int g0 = (bb & 31) * 4;
    int t = threadIdx.x;
    int q = t >> 6; int ii = (t >> 4) & 3; int d4 = t & 15;
    float4 acc = make_float4(0.f, 0.f, 0.f, 0.f);
    if (mode == 0) {
        int i = g0 + ii;
        float4 dvv = acc; bool hd = false;
        const float* base = in + ((size_t)(n * NN + i)) * NN * CC + d4 * 4;
        for (int j = q * 32; j < q * 32 + 32; ++j) {
            float4 v = *(const float4*)(base + (size_t)j * CC);
            acc.x += v.x; acc.y += v.y; acc.z += v.z; acc.w += v.w;
            if (j == i) { dvv = v; hd = true; }
        }
        if (hd) *(float4*)(ws + OFF_DV + ((size_t)(n * NN + i)) * CC + d4 * 4) = dvv;
    } else {
        int j = g0 + ii;
        unsigned short* xT = (unsigned short*)(ws + OFF_XT);
        for (int i = q * 32; i < q * 32 + 32; ++i) {
            float4 v = *(const float4*)(in + (((size_t)(n * NN + i)) * NN + j) * CC + d4 * 4);
            acc.x += v.x; acc.y += v.y; acc.z += v.z; acc.w += v.w;
            uint2 pk; pk.x = pack2bf(v.x, v.y); pk.y = pack2bf(v.z, v.w);
            *(uint2*)(xT + (((size_t)(n * NN + j)) * NN + i) * CC + d4 * 4) = pk;
        }
    }
    part[q][ii][d4] = acc;
    __syncthreads();
    if (t < 64) {
        int i2 = t >> 4; int dd = t & 15;
        float4 a = part[0][i2][dd], b = part[1][i2][dd], c = part[2][i2][dd], d = part[3][i2][dd];
        float4 s;
        s.x = (a.x + b.x + c.x + d.x) * INV_A;
        s.y = (a.y + b.y + c.y + d.y) * INV_A;
        s.z = (a.z + b.z + c.z + d.z) * INV_A;
        s.w = (a.w + b.w + c.w + d.w) * INV_A;
        *(float4*)(ws + (mode ? OFF_CS : OFF_RS) + ((size_t)(n * NN + g0 + i2)) * CC + dd * 4) = s;
    }
}

// ---------------------------------------------------------------------------
// K_uv: fused trace/allsum + broadcast-term GEMMs (R4-validated).
__global__ __launch_bounds__(256, 4) void k_uv(const float* __restrict__ bias,
                                               const float* __restrict__ dbias,
                                               float* __restrict__ ws) {
    __shared__ float trL[64], asL[64];
    __shared__ float pU1[4][4][64], pU2[4][4][64], pDG[4][4][64];
    __shared__ float pS[4][64], pDGc[4][64];
    int n = blockIdx.x >> 5; int i0 = (blockIdx.x & 31) * 4;
    int t = threadIdx.x;
    int s = t & 63; int q = t >> 6;

    {
        float tr = 0.f, as = 0.f;
        #pragma unroll 4
        for (int e = 0; e < 32; ++e) {
            int i = q * 32 + e;
            tr += ws[OFF_DV + ((size_t)(n * NN + i)) * CC + s];
            as += ws[OFF_RS + ((size_t)(n * NN + i)) * CC + s];
        }
        pS[q][s] = tr; pDGc[q][s] = as;
        __syncthreads();
        if (t < 64) {
            trL[t] = (pS[0][t] + pS[1][t] + pS[2][t] + pS[3][t]) * INV_A;
            asL[t] = (pDGc[0][t] + pDGc[1][t] + pDGc[2][t] + pDGc[3][t]) * INV_A;
        }
        __syncthreads();
    }

    const float* C = ws + OFF_C;
    float aU1[4] = {0, 0, 0, 0}, aU2[4] = {0, 0, 0, 0}, aDG[4] = {0, 0, 0, 0};
    float aS = 0.f, aDGc = 0.f;
    #pragma unroll
    for (int c4 = 0; c4 < 4; ++c4) {
        int dc = q * 4 + c4;
        float tr4[4], as4[4], dv4[4][4], rs4[4][4], cs4[4][4];
        #pragma unroll
        for (int k = 0; k < 4; ++k) { tr4[k] = trL[dc * 4 + k]; as4[k] = asL[dc * 4 + k]; }
        #pragma unroll
        for (int ii = 0; ii < 4; ++ii) {
            size_t ro = ((size_t)(n * NN + i0 + ii)) * CC + dc * 4;
            float4 v = *(const float4*)(ws + OFF_DV + ro);
            dv4[ii][0] = v.x; dv4[ii][1] = v.y; dv4[ii][2] = v.z; dv4[ii][3] = v.w;
            float4 r = *(const float4*)(ws + OFF_RS + ro);
            rs4[ii][0] = r.x; rs4[ii][1] = r.y; rs4[ii][2] = r.z; rs4[ii][3] = r.w;
            float4 c = *(const float4*)(ws + OFF_CS + ro);
            cs4[ii][0] = c.x; cs4[ii][1] = c.y; cs4[ii][2] = c.z; cs4[ii][3] = c.w;
        }
        #pragma unroll
        for (int k = 0; k < 4; ++k) {
            int d = dc * 4 + k;
            const float* Cd = C + d * 64 + s;
            float c0 = Cd[0 * 4096], c1 = Cd[1 * 4096], c2 = Cd[2 * 4096];
            float c5 = Cd[5 * 4096], c6 = Cd[6 * 4096], c7 = Cd[7 * 4096];
            float c8 = Cd[8 * 4096], c9 = Cd[9 * 4096], c10v = Cd[10 * 4096];
            float c11v = Cd[11 * 4096], c12v = Cd[12 * 4096];
            float c13 = Cd[13 * 4096], c14 = Cd[14 * 4096];
            aS += c13 * tr4[k] + c14 * as4[k];
            aDGc += c7 * tr4[k] + c8 * as4[k];
            #pragma unroll
            for (int ii = 0; ii < 4; ++ii) {
                aU1[ii] += c1 * dv4[ii][k] + c9 * rs4[ii][k] + c11v * cs4[ii][k];
                aU2[ii] += c2 * dv4[ii][k] + c10v * rs4[ii][k] + c12v * cs4[ii][k];
                aDG[ii] += c0 * dv4[ii][k] + c5 * rs4[ii][k] + c6 * cs4[ii][k];
            }
        }
    }
    #pragma unroll
    for (int ii = 0; ii < 4; ++ii) {
        pU1[q][ii][s] = aU1[ii]; pU2[q][ii][s] = aU2[ii]; pDG[q][ii][s] = aDG[ii];
    }
    pS[q][s] = aS; pDGc[q][s] = aDGc;
    __syncthreads();

    int fi = q;
    float u1 = pU1[0][fi][s] + pU1[1][fi][s] + pU1[2][fi][s] + pU1[3][fi][s];
    float u2 = pU2[0][fi][s] + pU2[1][fi][s] + pU2[2][fi][s] + pU2[3][fi][s];
    float dg = pDG[0][fi][s] + pDG[1][fi][s] + pDG[2][fi][s] + pDG[3][fi][s];
    float aSt = pS[0][s] + pS[1][s] + pS[2][s] + pS[3][s];
    float aDGct = pDGc[0][s] + pDGc[1][s] + pDGc[2][s] + pDGc[3][s];
    size_t row = ((size_t)(n * NN + i0 + fi)) * CC + s;
    ws[OFF_U1 + row] = u1 + aSt + bias[s];
    ws[OFF_U2 + row] = u2;
    ws[OFF_DG + row] = dg + aDGct + dbias[s];
}

// ---------------------------------------------------------------------------
// K_main (R4-validated): Block = (n, i, j-half): 64 pixels x 64 s, K=128.
// A[p][k] bf16 LDS: k<64 = x[n,i,j0+p,:] (fp32 input, packed here),
//                   k>=64 = x[n,j0+p,i,:] read COALESCED from XT bf16.
// B[s][k] bf16 LDS. Obuf aliases Ab (safe: wave-local dependency). 34 KB LDS.
__global__ __launch_bounds__(256, 4) void k_main(
        const float* __restrict__ in, const float* __restrict__ mask,
        const float* __restrict__ ws, float* __restrict__ out) {
    __shared__ __align__(16) unsigned char smem[34816];
    unsigned short* Ab = (unsigned short*)smem;            // 64 x 136 bf16
    unsigned short* Bb = (unsigned short*)(smem + 17408);  // 64 x 136 bf16
    float* Obuf = (float*)smem;                            // 64 x 68 fp32, aliases Ab

    int blk = blockIdx.x;
    int n = blk >> 8; int rem = blk & 255; int i = rem >> 1; int j0 = (rem & 1) * 64;
    int t = threadIdx.x;
    int tp = t >> 4; int c = t & 15;

    // ---- stage B: 64x128 bf16 from ws Cb (16 KB, L2-hot) ----
    const unsigned short* cb = (const unsigned short*)(ws + OFF_CB);
    #pragma unroll
    for (int e = 0; e < 4; ++e) {
        int s = e * 16 + tp;
        float4 v = *(const float4*)(cb + s * 128 + c * 8);     // raw 16B copy
        *(float4*)((unsigned char*)(Bb + s * 136 + c * 8)) = v;
    }
    // ---- stage A row-half: x[n,i,j0..j0+64,:] fp32 -> bf16 ----
    {
        const float* src = in + (((size_t)(n * NN + i)) * NN + j0) * CC;
        #pragma unroll
        for (int e = 0; e < 4; ++e) {
            int p = e * 16 + tp;
            float4 v = *(const float4*)(src + (size_t)p * CC + c * 4);
            uint2 pk; pk.x = pack2bf(v.x, v.y); pk.y = pack2bf(v.z, v.w);
            *(uint2*)(Ab + p * 136 + c * 4) = pk;
        }
    }
    // ---- stage A col-half: XT[n][i][j0+p][:] bf16, fully coalesced ----
    {
        const unsigned short* xT = (const unsigned short*)(ws + OFF_XT)
                                 + (((size_t)(n * NN + i)) * NN + j0) * CC;
        #pragma unroll
        for (int r = 0; r < 2; ++r) {
            int idx = t + r * 256;
            int p = idx >> 3; int ch = idx & 7;
            float4 v = *(const float4*)(xT + (size_t)p * CC + ch * 8);  // 8 bf16
            *(float4*)((unsigned char*)(Ab + p * 136 + 64 + ch * 8)) = v;
        }
    }
    __syncthreads();

    // ---- MFMA compute ----
    int w = t >> 6; int l = t & 63;
    int r16 = l & 15; int quad = l >> 4;
    v4f acc[4];
    #pragma unroll
    for (int st = 0; st < 4; ++st) acc[st] = 0.f;
    int arow = w * 16 + r16;
    #pragma unroll
    for (int kk = 0; kk < 4; ++kk) {
        v8s af = *(const v8s*)(Ab + arow * 136 + kk * 32 + quad * 8);
        #pragma unroll
        for (int st = 0; st < 4; ++st) {
            v8s bfr = *(const v8s*)(Bb + (st * 16 + r16) * 136 + kk * 32 + quad * 8);
            acc[st] = __builtin_amdgcn_mfma_f32_16x16x32_bf16(af, bfr, acc[st], 0, 0, 0);
        }
    }
    // acc -> Obuf (wave w writes only rows [w*16, w*16+16), which only it read)
    #pragma unroll
    for (int st = 0; st < 4; ++st)
        #pragma unroll
        for (int reg = 0; reg < 4; ++reg)
            Obuf[(w * 16 + quad * 4 + reg) * 68 + st * 16 + r16] = acc[st][reg];
    __syncthreads();

    // ---- epilogue: +U1[i] +U2[j] +(i==j)DG, leaky relu, mask, f4 store ----
    int srow = (n * NN + i) * CC;
    float4 u1 = *(const float4*)(ws + OFF_U1 + srow + c * 4);
    float4 dg = *(const float4*)(ws + OFF_DG + srow + c * 4);
    #pragma unroll
    for (int e = 0; e < 4; ++e) {
        int p = e * 16 + tp;
        int j = j0 + p;
        float4 v = *(const float4*)(Obuf + p * 68 + c * 4);
        float4 u2 = *(const float4*)(ws + OFF_U2 + (n * NN + j) * CC + c * 4);
        v.x += u1.x + u2.x; v.y += u1.y + u2.y; v.z += u1.z + u2.z; v.w += u1.w + u2.w;
        if (j == i) { v.x += dg.x; v.y += dg.y; v.z += dg.z; v.w += dg.w; }
        v.x = v.x > 0.f ? v.x : 0.01f * v.x;
        v.y = v.y > 0.f ? v.y : 0.01f * v.y;
        v.z = v.z > 0.f ? v.z : 0.01f * v.z;
        v.w = v.w > 0.f ? v.w : 0.01f * v.w;
        float m = mask[((size_t)(n * NN + i)) * NN + j];
        v.x *= m; v.y *= m; v.z *= m; v.w *= m;
        *(float4*)(out + (((size_t)(n * NN + i)) * NN + j) * CC + c * 4) = v;
    }
}

// ---------------------------------------------------------------------------
extern "C" void kernel_launch(void* const* d_in, const int* in_sizes, int n_in,
                              void* d_out, int out_size, void* d_ws, size_t ws_size,
                              hipStream_t stream) {
    const float* inputs = (const float*)d_in[0];
    const float* mask   = (const float*)d_in[1];
    // d_in[2] = nobj (unused by the reference computation)
    const float* c00 = (const float*)d_in[3];
    const float* c01 = (const float*)d_in[4];
    const float* c10 = (const float*)d_in[5];
    const float* c11 = (const float*)d_in[6];
    const float* bias  = (const float*)d_in[7];
    const float* dbias = (const float*)d_in[8];
    float* out = (float*)d_out;
    float* ws = (float*)d_ws;

    k_pre <<<784, 256, 0, stream>>>(inputs, c00, c01, c10, c11, ws);
    k_uv  <<<256, 256, 0, stream>>>(bias, dbias, ws);
    k_main<<<2048, 256, 0, stream>>>(inputs, mask, ws, out);
}